// Round 2
// baseline (187.469 us; speedup 1.0000x reference)
//
#include <hip/hip_runtime.h>

// TuckERInteraction: scores[n'] = sum_i u[n',i] * v[n',i]
//   v[n',i] = sum_j W[n'>>8, i, j] * t_bn[n', j]        (job A, grouped by k = n'>>8)
//   u[n',i] = sum_a h_bn[n',a] * r[(n'&255)*128+a, i]   (job B, grouped by low = n'&255)
// N = 32768, D = 128. V materialized in d_ws (bf16, 8 MB) + 512 flags (2 KB).
//
// R6: FUSED cooperative launch. Previous structure ran A and B as two serial
// kernels; ~80% of B (h/r staging + u-MFMA) is independent of V, so the
// boundary wasted that overlap + a launch gap. Now: one cooperative kernel,
// grid 512 x 256, 2 blocks/CU co-resident (guaranteed by cooperative launch
// -> flag-wait cannot deadlock). Each block: A job -> release flag ->
// B staging + u-MFMA (overlaps A stragglers) -> acquire-spin on the 64
// producer flags -> V-dot -> out. Flags memset to 0 in-stream (ws is
// poisoned every iteration).

typedef __attribute__((ext_vector_type(8))) short bf16x8;   // MFMA A/B fragment (8 bf16)
typedef __attribute__((ext_vector_type(4))) short s16x4;
typedef __attribute__((ext_vector_type(4))) float f32x4;

#define DPAD 136   // LDS row stride (elements); 68 dwords -> uniform 8/bank on b128 reads (BW-limit, no excess conflict)
#define BN_EPS 1e-5f

__device__ inline unsigned short f2bf(float f) {
  unsigned u = __builtin_bit_cast(unsigned, f);
  u += 0x7FFFu + ((u >> 16) & 1u);          // round-to-nearest-even
  return (unsigned short)(u >> 16);
}
__device__ inline float bf2f(unsigned short h) {
  unsigned u = ((unsigned)h) << 16;
  return __builtin_bit_cast(float, u);
}
__device__ inline unsigned pack2bf(float lo, float hi) {
  return (unsigned)f2bf(lo) | ((unsigned)f2bf(hi) << 16);
}

// Chunked XCD remap, nwg=512 (512%8==0 -> bijective).
__device__ inline int xcd_map(int bid) { return (bid & 7) * 64 + (bid >> 3); }

__global__ __launch_bounds__(256, 2) void k_fused(
    const float* __restrict__ t, const float* __restrict__ W,
    const float* __restrict__ gamma1, const float* __restrict__ beta1,
    const float* __restrict__ mean1, const float* __restrict__ var1,
    const float* __restrict__ h, const float* __restrict__ r,
    const float* __restrict__ gamma0, const float* __restrict__ beta0,
    const float* __restrict__ mean0, const float* __restrict__ var0,
    unsigned short* __restrict__ V, unsigned* __restrict__ flags,
    float* __restrict__ out) {
  __shared__ short LA[64 * DPAD];   // A: t_bn rows | B: h_bn rows
  __shared__ short LB[128 * DPAD];  // A: W[k] rows | B: r^T rows
  const int tid = threadIdx.x;
  const int c = tid & 31;
  const int rr = tid >> 5;
  const int wv_ = tid >> 6;
  const int lane = tid & 63;
  const int l16 = lane & 15;
  const int quad = lane >> 4;

  const int wg = xcd_map(blockIdx.x);

  // ================= Job A: V[n',i] = sum_j W[k,i,j] * t_bn[n',j] =================
  // wg -> (k = wg>>2, quarter = wg&3); 64 rows n' = k*256 + quarter*64 + m
  {
    const int k = wg >> 2;
    const int quarter = wg & 3;
    const int rowbase = k * 256 + quarter * 64;

    f32x4 g  = *(const f32x4*)(gamma1 + c * 4);
    f32x4 be = *(const f32x4*)(beta1  + c * 4);
    f32x4 mu = *(const f32x4*)(mean1  + c * 4);
    f32x4 va = *(const f32x4*)(var1   + c * 4);
    f32x4 sc, bi;
    for (int q = 0; q < 4; ++q) {
      sc[q] = g[q] * rsqrtf(va[q] + BN_EPS);
      bi[q] = be[q] - mu[q] * sc[q];
    }
    const float* tbase = t + (size_t)rowbase * 128;
    const float* wbase = W + (size_t)k * 16384;
#pragma unroll
    for (int it = 0; it < 8; ++it) {
      const int m = it * 8 + rr;
      f32x4 tv = *(const f32x4*)(tbase + m * 128 + c * 4);
      s16x4 tb;
      for (int q = 0; q < 4; ++q) tb[q] = (short)f2bf(tv[q] * sc[q] + bi[q]);
      *(s16x4*)(&LA[m * DPAD + c * 4]) = tb;
    }
#pragma unroll
    for (int it = 0; it < 16; ++it) {
      const int m = it * 8 + rr;
      f32x4 wvv = *(const f32x4*)(wbase + m * 128 + c * 4);
      s16x4 wb;
      for (int q = 0; q < 4; ++q) wb[q] = (short)f2bf(wvv[q]);
      *(s16x4*)(&LB[m * DPAD + c * 4]) = wb;
    }
    __syncthreads();

    f32x4 acc[8];
#pragma unroll
    for (int nt = 0; nt < 8; ++nt) acc[nt] = (f32x4){0.f, 0.f, 0.f, 0.f};

    // swapped operands: acc = mfma(Wfrag, Tfrag) -> D[i-part(row), n'-part(col)]
    __builtin_amdgcn_s_setprio(1);
#pragma unroll
    for (int ks = 0; ks < 4; ++ks) {
      const int K0 = ks * 32 + quad * 8;
      bf16x8 a = *(const bf16x8*)(&LA[(wv_ * 16 + l16) * DPAD + K0]);
      bf16x8 b[8];
#pragma unroll
      for (int nt = 0; nt < 8; ++nt)
        b[nt] = *(const bf16x8*)(&LB[(nt * 16 + l16) * DPAD + K0]);
#pragma unroll
      for (int nt = 0; nt < 8; ++nt)
        acc[nt] = __builtin_amdgcn_mfma_f32_16x16x32_bf16(b[nt], a, acc[nt], 0, 0, 0);
    }
    __builtin_amdgcn_s_setprio(0);

    // lane holds i = nt*16 + quad*4 + {0..3} of row n' = rowbase + wv*16 + l16
    const size_t np = (size_t)(rowbase + wv_ * 16 + l16) * 128;
#pragma unroll
    for (int nt = 0; nt < 8; ++nt) {
      unsigned two[2];
      two[0] = pack2bf(acc[nt][0], acc[nt][1]);
      two[1] = pack2bf(acc[nt][2], acc[nt][3]);
      *(uint2*)(V + np + nt * 16 + quad * 4) = *(uint2*)two;
    }
  }

  // barrier drains all waves' V stores (syncthreads implies vmcnt(0) drain);
  // then one agent-scope release publishes them (wbL2 before the store).
  __syncthreads();
  if (tid == 0)
    __hip_atomic_store(&flags[wg], 1u, __ATOMIC_RELEASE, __HIP_MEMORY_SCOPE_AGENT);

  // ============ Job B: out[n'] = sum_i (sum_a h_bn[n',a] r[low*128+a,i]) * V[n',i] ============
  // wg -> (low = wg>>1, half = wg&1); rows n' = kk*256 + low, kk = half*64 + [0,64)
  {
    const int low = wg >> 1;
    const int half = wg & 1;
    const int kkbase = half * 64;

    f32x4 g  = *(const f32x4*)(gamma0 + c * 4);
    f32x4 be = *(const f32x4*)(beta0  + c * 4);
    f32x4 mu = *(const f32x4*)(mean0  + c * 4);
    f32x4 va = *(const f32x4*)(var0   + c * 4);
    f32x4 sc, bi;
    for (int q = 0; q < 4; ++q) {
      sc[q] = g[q] * rsqrtf(va[q] + BN_EPS);
      bi[q] = be[q] - mu[q] * sc[q];
    }
#pragma unroll
    for (int it = 0; it < 8; ++it) {
      const int kkloc = it * 8 + rr;
      f32x4 hv = *(const f32x4*)(h + ((size_t)(kkbase + kkloc) * 256 + low) * 128 + c * 4);
      s16x4 hb;
      for (int q = 0; q < 4; ++q) hb[q] = (short)f2bf(hv[q] * sc[q] + bi[q]);
      *(s16x4*)(&LA[kkloc * DPAD + c * 4]) = hb;
    }
    // transpose-stage r: thread owns 4x4 block (rows a0..a0+3, cols 4c..4c+3)
#pragma unroll
    for (int it = 0; it < 4; ++it) {
      const int a0 = it * 32 + rr * 4;
      f32x4 rv[4];
      for (int v = 0; v < 4; ++v)
        rv[v] = *(const f32x4*)(r + ((size_t)(low * 128 + a0 + v)) * 128 + c * 4);
      for (int u = 0; u < 4; ++u) {
        s16x4 w;
        for (int v = 0; v < 4; ++v) w[v] = (short)f2bf(rv[v][u]);
        *(s16x4*)(&LB[(c * 4 + u) * DPAD + a0]) = w;
      }
    }
    __syncthreads();

    f32x4 acc[8];
#pragma unroll
    for (int nt = 0; nt < 8; ++nt) acc[nt] = (f32x4){0.f, 0.f, 0.f, 0.f};

    // swapped operands: acc = mfma(Rfrag, Hfrag) -> D[i-part(row), kk-part(col)]
    __builtin_amdgcn_s_setprio(1);
#pragma unroll
    for (int ks = 0; ks < 4; ++ks) {
      const int K0 = ks * 32 + quad * 8;
      bf16x8 a = *(const bf16x8*)(&LA[(wv_ * 16 + l16) * DPAD + K0]);
      bf16x8 b[8];
#pragma unroll
      for (int nt = 0; nt < 8; ++nt)
        b[nt] = *(const bf16x8*)(&LB[(nt * 16 + l16) * DPAD + K0]);
#pragma unroll
      for (int nt = 0; nt < 8; ++nt)
        acc[nt] = __builtin_amdgcn_mfma_f32_16x16x32_bf16(b[nt], a, acc[nt], 0, 0, 0);
    }
    __builtin_amdgcn_s_setprio(0);

    // Wait for the 64 producer A-jobs this B-job consumes:
    // k in [kkbase, kkbase+64), quarter = low>>6 -> job id = (k<<2)|quarter.
    if (tid < 64) {
      const int pid = ((kkbase + tid) << 2) | (low >> 6);
      while (__hip_atomic_load(&flags[pid], __ATOMIC_ACQUIRE,
                               __HIP_MEMORY_SCOPE_AGENT) == 0u)
        __builtin_amdgcn_s_sleep(2);
    }
    __syncthreads();
    __builtin_amdgcn_fence(__ATOMIC_ACQUIRE, "agent");  // propagate inv to all threads

    // fused dot: lane holds u[n', i=nt*16+quad*4+q] fp32 for row n' = kk*256+low,
    // kk = kkbase + wv*16 + l16. Load matching V bf16, FMA, reduce across quads.
    const int kk = kkbase + wv_ * 16 + l16;
    const size_t np = ((size_t)kk * 256 + low) * 128;
    float s = 0.f;
#pragma unroll
    for (int nt = 0; nt < 8; ++nt) {
      const uint2 vv = *(const uint2*)(V + np + nt * 16 + quad * 4);
      s += acc[nt][0] * bf2f((unsigned short)(vv.x & 0xFFFFu));
      s += acc[nt][1] * bf2f((unsigned short)(vv.x >> 16));
      s += acc[nt][2] * bf2f((unsigned short)(vv.y & 0xFFFFu));
      s += acc[nt][3] * bf2f((unsigned short)(vv.y >> 16));
    }
    s += __shfl_xor(s, 16, 64);
    s += __shfl_xor(s, 32, 64);
    if (quad == 0) out[(size_t)kk * 256 + low] = s;
  }
}

extern "C" void kernel_launch(void* const* d_in, const int* in_sizes, int n_in,
                              void* d_out, int out_size, void* d_ws, size_t ws_size,
                              hipStream_t stream) {
  const float* h      = (const float*)d_in[0];
  const float* r      = (const float*)d_in[1];
  const float* t      = (const float*)d_in[2];
  const float* W      = (const float*)d_in[3];
  const float* gamma0 = (const float*)d_in[4];
  const float* beta0  = (const float*)d_in[5];
  const float* mean0  = (const float*)d_in[6];
  const float* var0   = (const float*)d_in[7];
  const float* gamma1 = (const float*)d_in[8];
  const float* beta1  = (const float*)d_in[9];
  const float* mean1  = (const float*)d_in[10];
  const float* var1   = (const float*)d_in[11];
  float* out = (float*)d_out;

  unsigned short* V = (unsigned short*)d_ws;                 // 32768*128 bf16 = 8 MB
  unsigned* flags = (unsigned*)((char*)d_ws + (size_t)32768 * 128 * 2);  // 512 flags

  // ws is poisoned to garbage every iteration -> zero the flags in-stream.
  hipMemsetAsync(flags, 0, 512 * sizeof(unsigned), stream);

  void* args[] = {(void*)&t, (void*)&W, (void*)&gamma1, (void*)&beta1,
                  (void*)&mean1, (void*)&var1, (void*)&h, (void*)&r,
                  (void*)&gamma0, (void*)&beta0, (void*)&mean0, (void*)&var0,
                  (void*)&V, (void*)&flags, (void*)&out};
  hipLaunchCooperativeKernel((const void*)k_fused, dim3(512), dim3(256),
                             args, 0, stream);
}

// Round 4
// 138.116 us; speedup vs baseline: 1.3573x; 1.3573x over previous
//
#include <hip/hip_runtime.h>

// TuckERInteraction: scores[n'] = sum_i u[n',i] * v[n',i]
//   v[n',i] = sum_j W[n'>>8, i, j] * t_bn[n', j]              (k_vA, k = n'>>8)
//   out[n'] = sum_a h_bn[n',a] * (sum_i r[low,a,i] * v[n',i]) (k_B2, low = n'&255)
// N = 32768, D = 128. ws usage: V only (bf16, 8 MB) — the proven footprint.
//
// R8: wave-independent, LDS-free, barrier-free (R6 counters: the LDS/barrier
// chain was pure latency exposure — 650 GB/s, MfmaUtil 1.2%). R7's prep-pass
// variant OOB'd the workspace (36 MB > ws_size) and corrupted inputs across
// graph replays; R8 keeps the structure but converts f32->bf16 IN-REGISTER at
// fragment build, so no extra ws. The r-transpose is eliminated algebraically:
// contract over i first (G[a][n'] = sum_i r*V; both contiguous in i), then
// dot with f32 h_bn in the epilogue. 2048 independent waves per kernel,
// 8 waves/CU, one load burst -> MFMA burst per wave.

typedef __attribute__((ext_vector_type(8))) short bf16x8;   // MFMA A/B fragment (8 bf16)
typedef __attribute__((ext_vector_type(4))) float f32x4;

#define BN_EPS 1e-5f

__device__ inline unsigned short f2bf(float f) {
  unsigned u = __builtin_bit_cast(unsigned, f);
  u += 0x7FFFu + ((u >> 16) & 1u);          // round-to-nearest-even
  return (unsigned short)(u >> 16);
}
__device__ inline unsigned pack2bf(float lo, float hi) {
  return (unsigned)f2bf(lo) | ((unsigned)f2bf(hi) << 16);
}
__device__ inline bf16x8 cvt8(f32x4 lo, f32x4 hi) {
  bf16x8 o;
  o[0] = (short)f2bf(lo[0]); o[1] = (short)f2bf(lo[1]);
  o[2] = (short)f2bf(lo[2]); o[3] = (short)f2bf(lo[3]);
  o[4] = (short)f2bf(hi[0]); o[5] = (short)f2bf(hi[1]);
  o[6] = (short)f2bf(hi[2]); o[7] = (short)f2bf(hi[3]);
  return o;
}

// Chunked XCD remap, nwg=512 (512%8==0 -> bijective): waves sharing W[k] /
// r[low] land on the same XCD's L2.
__device__ inline int xcd_map(int bid) { return (bid & 7) * 64 + (bid >> 3); }

// ---------------- k_vA: V[n',i] = sum_j W[k,i,j] * t_bn[n',j] ----------------
// 2048 waves; wave w: k = w>>4, rg = w&15; 16 rows n' = k*256 + rg*16 + l16.
// No LDS, no barriers; fragments built from global f32 with in-register cvt.
__global__ __launch_bounds__(256) void k_vA(
    const float* __restrict__ t, const float* __restrict__ W,
    const float* __restrict__ gamma1, const float* __restrict__ beta1,
    const float* __restrict__ mean1, const float* __restrict__ var1,
    unsigned short* __restrict__ V) {
  const int tid = threadIdx.x;
  const int wv_ = tid >> 6;
  const int lane = tid & 63;
  const int l16 = lane & 15;
  const int quad = lane >> 4;

  const int w = xcd_map(blockIdx.x) * 4 + wv_;
  const int k = w >> 4;
  const int rg = w & 15;
  const int nrow = k * 256 + rg * 16 + l16;

  // T-fragments (BN1 applied, bf16) for all 4 k-slices up front.
  // Param loads are quad-uniform (4 distinct addrs/instr) -> L1 broadcast.
  const float* tp = t + (size_t)nrow * 128;
  bf16x8 tf[4];
#pragma unroll
  for (int ks = 0; ks < 4; ++ks) {
    const int K0 = ks * 32 + quad * 8;
    f32x4 g0 = *(const f32x4*)(gamma1 + K0), g1 = *(const f32x4*)(gamma1 + K0 + 4);
    f32x4 b0 = *(const f32x4*)(beta1  + K0), b1 = *(const f32x4*)(beta1  + K0 + 4);
    f32x4 m0 = *(const f32x4*)(mean1  + K0), m1 = *(const f32x4*)(mean1  + K0 + 4);
    f32x4 v0 = *(const f32x4*)(var1   + K0), v1 = *(const f32x4*)(var1   + K0 + 4);
    f32x4 t0 = *(const f32x4*)(tp + K0),     t1 = *(const f32x4*)(tp + K0 + 4);
    f32x4 lo, hi;
    for (int q = 0; q < 4; ++q) {
      const float s0 = g0[q] * rsqrtf(v0[q] + BN_EPS);
      lo[q] = t0[q] * s0 + (b0[q] - m0[q] * s0);
      const float s1 = g1[q] * rsqrtf(v1[q] + BN_EPS);
      hi[q] = t1[q] * s1 + (b1[q] - m1[q] * s1);
    }
    tf[ks] = cvt8(lo, hi);
  }

  const float* wp = W + (size_t)k * 16384 + (size_t)l16 * 128;

  f32x4 acc[8];
#pragma unroll
  for (int nt = 0; nt < 8; ++nt) acc[nt] = (f32x4){0.f, 0.f, 0.f, 0.f};

  // swapped operands: acc = mfma(Wfrag, Tfrag) -> D[i-part(row), n'-part(col)]
#pragma unroll
  for (int ks = 0; ks < 4; ++ks) {
    const int K0 = ks * 32 + quad * 8;
#pragma unroll
    for (int nt = 0; nt < 8; ++nt) {
      f32x4 w0 = *(const f32x4*)(wp + nt * 2048 + K0);
      f32x4 w1 = *(const f32x4*)(wp + nt * 2048 + K0 + 4);
      acc[nt] = __builtin_amdgcn_mfma_f32_16x16x32_bf16(cvt8(w0, w1), tf[ks],
                                                        acc[nt], 0, 0, 0);
    }
  }

  // lane holds i = nt*16 + quad*4 + {0..3} of row n' = nrow
  const size_t np = (size_t)nrow * 128;
#pragma unroll
  for (int nt = 0; nt < 8; ++nt) {
    unsigned two[2];
    two[0] = pack2bf(acc[nt][0], acc[nt][1]);
    two[1] = pack2bf(acc[nt][2], acc[nt][3]);
    *(uint2*)(V + np + nt * 16 + quad * 4) = *(uint2*)two;
  }
}

// ---- k_B2: G[a][n'] = sum_i r[low,a,i]*V[n',i]; out[n'] = sum_a h_bn[n',a]*G[a][n'] ----
// 2048 waves; wave w: low = w>>3, kg = w&7; 16 cols n' = (kg*16+l16)*256 + low.
// Contraction over i (both r and V contiguous in i) -> no transpose needed.
__global__ __launch_bounds__(256) void k_B2(
    const float* __restrict__ h, const float* __restrict__ r,
    const float* __restrict__ gamma0, const float* __restrict__ beta0,
    const float* __restrict__ mean0, const float* __restrict__ var0,
    const unsigned short* __restrict__ V, float* __restrict__ out) {
  const int tid = threadIdx.x;
  const int wv_ = tid >> 6;
  const int lane = tid & 63;
  const int l16 = lane & 15;
  const int quad = lane >> 4;

  const int w = xcd_map(blockIdx.x) * 4 + wv_;
  const int low = w >> 3;
  const int kg = w & 7;
  const int kk = kg * 16 + l16;
  const size_t nprow = (size_t)kk * 256 + low;

  // V fragments (B operand over K=i): lane holds V[n'(l16)][ks*32+quad*8 + 0..7]
  const unsigned short* vp = V + nprow * 128;
  bf16x8 vf[4];
#pragma unroll
  for (int ks = 0; ks < 4; ++ks)
    vf[ks] = *(const bf16x8*)(vp + ks * 32 + quad * 8);

  // r fragments (A operand, rows a = nt*16 + l16, K=i contiguous in memory)
  const float* rp = r + ((size_t)low * 128 + l16) * 128;

  f32x4 acc[8];
#pragma unroll
  for (int nt = 0; nt < 8; ++nt) acc[nt] = (f32x4){0.f, 0.f, 0.f, 0.f};

  // acc = mfma(Rfrag, Vfrag) -> D[a-part(row), n'-part(col)]
#pragma unroll
  for (int ks = 0; ks < 4; ++ks) {
    const int K0 = ks * 32 + quad * 8;
#pragma unroll
    for (int nt = 0; nt < 8; ++nt) {
      f32x4 r0 = *(const f32x4*)(rp + nt * 2048 + K0);
      f32x4 r1 = *(const f32x4*)(rp + nt * 2048 + K0 + 4);
      acc[nt] = __builtin_amdgcn_mfma_f32_16x16x32_bf16(cvt8(r0, r1), vf[ks],
                                                        acc[nt], 0, 0, 0);
    }
  }

  // Epilogue: lane holds G[a = nt*16+quad*4+q][n'(l16)]. Dot with f32 h_bn,
  // reduce the a-partition across quads (lane bits 4,5), lane<16 writes out.
  const float* hp = h + nprow * 128;
  float s = 0.f;
#pragma unroll
  for (int nt = 0; nt < 8; ++nt) {
    const int a0 = nt * 16 + quad * 4;
    f32x4 hv = *(const f32x4*)(hp + a0);
    f32x4 g  = *(const f32x4*)(gamma0 + a0);
    f32x4 be = *(const f32x4*)(beta0  + a0);
    f32x4 mu = *(const f32x4*)(mean0  + a0);
    f32x4 va = *(const f32x4*)(var0   + a0);
    for (int q = 0; q < 4; ++q) {
      const float sc = g[q] * rsqrtf(va[q] + BN_EPS);
      const float hb = hv[q] * sc + (be[q] - mu[q] * sc);
      s += hb * acc[nt][q];
    }
  }
  s += __shfl_xor(s, 16, 64);
  s += __shfl_xor(s, 32, 64);
  if (quad == 0) out[nprow] = s;
}

extern "C" void kernel_launch(void* const* d_in, const int* in_sizes, int n_in,
                              void* d_out, int out_size, void* d_ws, size_t ws_size,
                              hipStream_t stream) {
  const float* h      = (const float*)d_in[0];
  const float* r      = (const float*)d_in[1];
  const float* t      = (const float*)d_in[2];
  const float* W      = (const float*)d_in[3];
  const float* gamma0 = (const float*)d_in[4];
  const float* beta0  = (const float*)d_in[5];
  const float* mean0  = (const float*)d_in[6];
  const float* var0   = (const float*)d_in[7];
  const float* gamma1 = (const float*)d_in[8];
  const float* beta1  = (const float*)d_in[9];
  const float* mean1  = (const float*)d_in[10];
  const float* var1   = (const float*)d_in[11];
  float* out = (float*)d_out;

  unsigned short* V = (unsigned short*)d_ws;   // 32768*128 bf16 = 8 MB (proven footprint)

  k_vA<<<512, 256, 0, stream>>>(t, W, gamma1, beta1, mean1, var1, V);
  k_B2<<<512, 256, 0, stream>>>(h, r, gamma0, beta0, mean0, var0, V, out);
}

// Round 6
// 118.535 us; speedup vs baseline: 1.5815x; 1.1652x over previous
//
#include <hip/hip_runtime.h>

// TuckERInteraction: scores[n'] = sum_i u[n',i] * v[n',i]
//   v[n',i] = sum_j W[n'>>8, i, j] * t_bn[n', j]               (k_A, k = n'>>8)
//   out[n'] = sum_a h_bn[n',a] * (sum_i r[low,a,i] * v[n',i])  (k_B, low = n'&255)
// N = 32768, D = 128. ws: V only (bf16, 8 MB) — proven footprint. No sync tricks.
//
// R10: phase-structure fix inside the safe two-kernel skeleton.
//  Evidence: R6 counters (650 GB/s, MfmaUtil 1.2%, VALU 4.9%, 90% stall,
//  1.5M LDS-conflict cycles) + R5 (occupancy 2x: no change) => blocks stall in
//  serial non-load phases, not on occupancy. Changes vs R4:
//   - t (A) and h/V (B) are NOT LDS-staged: t-fragments load directly into
//     MFMA regs (block-exclusive data, staging bought nothing); issued before
//     the W staging so they overlap it.
//   - B uses i-first contraction (R8's k_B2, passed): G[a][n'] = sum_i r*V,
//     then out = sum_a h_bn*G. r stages NATURALLY row-major (coalesced,
//     no transpose => kills the 16-way-conflict LDS writes); V fragments and
//     h epilogue reads are scattered 16B but L3-absorbed (<=16MB each, read
//     once). V visibility across XCDs is free at the kernel boundary.
//   - LDS 52->34.8 KB, one barrier phase gone, launch_bounds(256,3).
//  Grid 512 each (64 rows/block), chunked XCD swizzle (blocks sharing W[k] /
//  r[low] on one XCD's L2).

typedef __attribute__((ext_vector_type(8))) short bf16x8;   // MFMA A/B fragment (8 bf16)
typedef __attribute__((ext_vector_type(4))) short s16x4;
typedef __attribute__((ext_vector_type(4))) float f32x4;

#define DPAD 136   // LDS row stride (elements)
#define BN_EPS 1e-5f

__device__ inline unsigned short f2bf(float f) {
  unsigned u = __builtin_bit_cast(unsigned, f);
  u += 0x7FFFu + ((u >> 16) & 1u);          // round-to-nearest-even
  return (unsigned short)(u >> 16);
}
__device__ inline float bf2f(unsigned short h) {
  unsigned u = ((unsigned)h) << 16;
  return __builtin_bit_cast(float, u);
}
__device__ inline unsigned pack2bf(float lo, float hi) {
  return (unsigned)f2bf(lo) | ((unsigned)f2bf(hi) << 16);
}
__device__ inline bf16x8 cvt8(f32x4 lo, f32x4 hi) {
  bf16x8 o;
  o[0] = (short)f2bf(lo[0]); o[1] = (short)f2bf(lo[1]);
  o[2] = (short)f2bf(lo[2]); o[3] = (short)f2bf(lo[3]);
  o[4] = (short)f2bf(hi[0]); o[5] = (short)f2bf(hi[1]);
  o[6] = (short)f2bf(hi[2]); o[7] = (short)f2bf(hi[3]);
  return o;
}

// Chunked XCD remap, nwg=512 (512%8==0 -> bijective).
__device__ inline int xcd_map(int bid) { return (bid & 7) * 64 + (bid >> 3); }

// ---------------- k_A: V[n',i] = sum_j W[k,i,j] * t_bn[n',j] ----------------
// grid 512: wg = (k<<2)|quarter; 64 rows n' = k*256 + quarter*64 + wv*16 + l16.
__global__ __launch_bounds__(256, 3) void k_A(
    const float* __restrict__ t, const float* __restrict__ W,
    const float* __restrict__ gamma1, const float* __restrict__ beta1,
    const float* __restrict__ mean1, const float* __restrict__ var1,
    unsigned short* __restrict__ V) {
  __shared__ short LW[128 * DPAD];  // Wl[i][j] = bf16(W[k,i,j]), natural layout
  const int tid = threadIdx.x;
  const int c = tid & 31;
  const int rr = tid >> 5;
  const int wv_ = tid >> 6;
  const int lane = tid & 63;
  const int l16 = lane & 15;
  const int quad = lane >> 4;

  const int wg = xcd_map(blockIdx.x);
  const int k = wg >> 2;
  const int quarter = wg & 3;
  const int nrow = k * 256 + quarter * 64 + wv_ * 16 + l16;

  // (1) direct t fragments with BN applied, in-register cvt — independent of
  // the LDS staging below, so these loads overlap it.
  const float* tp = t + (size_t)nrow * 128;
  bf16x8 tf[4];
#pragma unroll
  for (int ks = 0; ks < 4; ++ks) {
    const int K0 = ks * 32 + quad * 8;
    f32x4 g0 = *(const f32x4*)(gamma1 + K0), g1 = *(const f32x4*)(gamma1 + K0 + 4);
    f32x4 b0 = *(const f32x4*)(beta1  + K0), b1 = *(const f32x4*)(beta1  + K0 + 4);
    f32x4 m0 = *(const f32x4*)(mean1  + K0), m1 = *(const f32x4*)(mean1  + K0 + 4);
    f32x4 v0 = *(const f32x4*)(var1   + K0), v1 = *(const f32x4*)(var1   + K0 + 4);
    f32x4 t0 = *(const f32x4*)(tp + K0),     t1 = *(const f32x4*)(tp + K0 + 4);
    f32x4 lo, hi;
    for (int q = 0; q < 4; ++q) {
      const float s0 = g0[q] * rsqrtf(v0[q] + BN_EPS);
      lo[q] = t0[q] * s0 + (b0[q] - m0[q] * s0);
      const float s1 = g1[q] * rsqrtf(v1[q] + BN_EPS);
      hi[q] = t1[q] * s1 + (b1[q] - m1[q] * s1);
    }
    tf[ks] = cvt8(lo, hi);
  }

  // (2) stage W[k] -> LDS bf16 (coalesced 16B loads, natural row-major)
  const float* wbase = W + (size_t)k * 16384;
#pragma unroll
  for (int it = 0; it < 16; ++it) {
    const int m = it * 8 + rr;
    f32x4 wvv = *(const f32x4*)(wbase + m * 128 + c * 4);
    s16x4 wb;
    for (int q = 0; q < 4; ++q) wb[q] = (short)f2bf(wvv[q]);
    *(s16x4*)(&LW[m * DPAD + c * 4]) = wb;
  }
  __syncthreads();

  // (3) MFMA: acc = mfma(Wfrag, Tfrag) -> D[i-part(row), n'-part(col)]
  f32x4 acc[8];
#pragma unroll
  for (int nt = 0; nt < 8; ++nt) acc[nt] = (f32x4){0.f, 0.f, 0.f, 0.f};

  __builtin_amdgcn_s_setprio(1);
#pragma unroll
  for (int ks = 0; ks < 4; ++ks) {
    const int K0 = ks * 32 + quad * 8;
    bf16x8 b[8];
#pragma unroll
    for (int nt = 0; nt < 8; ++nt)
      b[nt] = *(const bf16x8*)(&LW[(nt * 16 + l16) * DPAD + K0]);
#pragma unroll
    for (int nt = 0; nt < 8; ++nt)
      acc[nt] = __builtin_amdgcn_mfma_f32_16x16x32_bf16(b[nt], tf[ks], acc[nt], 0, 0, 0);
  }
  __builtin_amdgcn_s_setprio(0);

  // (4) lane holds i = nt*16 + quad*4 + {0..3} of row n' = nrow
  const size_t np = (size_t)nrow * 128;
#pragma unroll
  for (int nt = 0; nt < 8; ++nt) {
    unsigned two[2];
    two[0] = pack2bf(acc[nt][0], acc[nt][1]);
    two[1] = pack2bf(acc[nt][2], acc[nt][3]);
    *(uint2*)(V + np + nt * 16 + quad * 4) = *(uint2*)two;
  }
}

// ---- k_B: G[a][n'] = sum_i r[low,a,i]*V[n',i]; out[n'] = sum_a h_bn[n',a]*G[a][n'] ----
// grid 512: wg = (low<<1)|half; 64 rows kk = half*64 + wv*16 + l16, n' = kk*256+low.
__global__ __launch_bounds__(256, 3) void k_B(
    const float* __restrict__ h, const float* __restrict__ r,
    const float* __restrict__ gamma0, const float* __restrict__ beta0,
    const float* __restrict__ mean0, const float* __restrict__ var0,
    const unsigned short* __restrict__ V, float* __restrict__ out) {
  __shared__ short LR[128 * DPAD];  // Rl[a][i] = bf16(r[low*128+a, i]), natural layout
  const int tid = threadIdx.x;
  const int c = tid & 31;
  const int rr = tid >> 5;
  const int wv_ = tid >> 6;
  const int lane = tid & 63;
  const int l16 = lane & 15;
  const int quad = lane >> 4;

  const int wg = xcd_map(blockIdx.x);
  const int low = wg >> 1;
  const int half = wg & 1;
  const int kk = half * 64 + wv_ * 16 + l16;
  const size_t nprow = (size_t)kk * 256 + low;

  // (1) direct V fragments (B operand over K=i): lane holds V[n'(l16)][K0..K0+8].
  // Scattered 16B reads (64KB lane stride) — L2/L3-served, V read once (8MB).
  const unsigned short* vp = V + nprow * 128;
  bf16x8 vf[4];
#pragma unroll
  for (int ks = 0; ks < 4; ++ks)
    vf[ks] = *(const bf16x8*)(vp + ks * 32 + quad * 8);

  // (2) stage r[low] -> LDS bf16 — NATURAL row-major [a][i], fully coalesced,
  // no transpose (the 16-way-conflict writes of R4-R6 are gone).
  const float* rbase = r + (size_t)low * 16384;
#pragma unroll
  for (int it = 0; it < 16; ++it) {
    const int m = it * 8 + rr;
    f32x4 rv = *(const f32x4*)(rbase + m * 128 + c * 4);
    s16x4 rb;
    for (int q = 0; q < 4; ++q) rb[q] = (short)f2bf(rv[q]);
    *(s16x4*)(&LR[m * DPAD + c * 4]) = rb;
  }
  __syncthreads();

  // (3) MFMA: acc = mfma(Rfrag, Vfrag) -> D[a-part(row), kk-part(col)]
  f32x4 acc[8];
#pragma unroll
  for (int nt = 0; nt < 8; ++nt) acc[nt] = (f32x4){0.f, 0.f, 0.f, 0.f};

  __builtin_amdgcn_s_setprio(1);
#pragma unroll
  for (int ks = 0; ks < 4; ++ks) {
    const int K0 = ks * 32 + quad * 8;
    bf16x8 b[8];
#pragma unroll
    for (int nt = 0; nt < 8; ++nt)
      b[nt] = *(const bf16x8*)(&LR[(nt * 16 + l16) * DPAD + K0]);
#pragma unroll
    for (int nt = 0; nt < 8; ++nt)
      acc[nt] = __builtin_amdgcn_mfma_f32_16x16x32_bf16(b[nt], vf[ks], acc[nt], 0, 0, 0);
  }
  __builtin_amdgcn_s_setprio(0);

  // (4) epilogue: lane holds G[a = nt*16+quad*4+q][n'(l16)]. Dot with f32
  // h_bn (R8's passed epilogue), reduce a-partition across quads, write out.
  const float* hp = h + nprow * 128;
  float s = 0.f;
#pragma unroll
  for (int nt = 0; nt < 8; ++nt) {
    const int a0 = nt * 16 + quad * 4;
    f32x4 hv = *(const f32x4*)(hp + a0);
    f32x4 g  = *(const f32x4*)(gamma0 + a0);
    f32x4 be = *(const f32x4*)(beta0  + a0);
    f32x4 mu = *(const f32x4*)(mean0  + a0);
    f32x4 va = *(const f32x4*)(var0   + a0);
    for (int q = 0; q < 4; ++q) {
      const float sc = g[q] * rsqrtf(va[q] + BN_EPS);
      const float hb = hv[q] * sc + (be[q] - mu[q] * sc);
      s += hb * acc[nt][q];
    }
  }
  s += __shfl_xor(s, 16, 64);
  s += __shfl_xor(s, 32, 64);
  if (quad == 0) out[nprow] = s;
}

extern "C" void kernel_launch(void* const* d_in, const int* in_sizes, int n_in,
                              void* d_out, int out_size, void* d_ws, size_t ws_size,
                              hipStream_t stream) {
  const float* h      = (const float*)d_in[0];
  const float* r      = (const float*)d_in[1];
  const float* t      = (const float*)d_in[2];
  const float* W      = (const float*)d_in[3];
  const float* gamma0 = (const float*)d_in[4];
  const float* beta0  = (const float*)d_in[5];
  const float* mean0  = (const float*)d_in[6];
  const float* var0   = (const float*)d_in[7];
  const float* gamma1 = (const float*)d_in[8];
  const float* beta1  = (const float*)d_in[9];
  const float* mean1  = (const float*)d_in[10];
  const float* var1   = (const float*)d_in[11];
  float* out = (float*)d_out;

  unsigned short* V = (unsigned short*)d_ws;   // 32768*128 bf16 = 8 MB (proven footprint)

  k_A<<<512, 256, 0, stream>>>(t, W, gamma1, beta1, mean1, var1, V);
  k_B<<<512, 256, 0, stream>>>(h, r, gamma0, beta0, mean0, var0, V, out);
}

// Round 7
// 115.914 us; speedup vs baseline: 1.6173x; 1.0226x over previous
//
#include <hip/hip_runtime.h>

// TuckERInteraction: scores[n'] = sum_i u[n',i] * v[n',i]
//   v[n',i] = sum_j W[n'>>8, i, j] * t_bn[n', j]        (stage A, grouped by k = n'>>8)
//   u[n',i] = sum_a h_bn[n',a] * r[(n'&255)*128+a, i]   (stage B, grouped by low = n'&255)
// N = 32768, D = 128. ws: V only (bf16, 8 MB).
//
// R11 = R4 (best, 114.5) + DEEP LOAD BATCHING. Ledger: occupancy 1->2->3
// blocks/CU neutral (R5/R10); phase merges neutral (R10); LDS-free -24%
// (R8); fused kernel 64.9us with MfmaUtil 1.2%/VALU 4.9% (R6) => the pair
// is ~65-73us of exposed memory latency. Little's law needs ~22KB/CU
// outstanding for 6.3TB/s; the old {load;cvt;ds_write} loops pipeline only
// ~2-3 deep (VGPR=68). Fix: issue ALL staging loads as one register-batched
// burst (32x f32x4 = 32KB/wave in flight; 128KB/CU at 4 waves), one vmcnt
// wall, then cvt+LDS-write. launch_bounds(256,2) caps VGPR at 256 (no spill
// at ~190). Everything else byte-identical to R4.

typedef __attribute__((ext_vector_type(8))) short bf16x8;   // MFMA A/B fragment (8 bf16)
typedef __attribute__((ext_vector_type(4))) short s16x4;
typedef __attribute__((ext_vector_type(4))) float f32x4;

#define DPAD 136   // LDS row stride (elements)
#define BN_EPS 1e-5f

__device__ inline unsigned short f2bf(float f) {
  unsigned u = __builtin_bit_cast(unsigned, f);
  u += 0x7FFFu + ((u >> 16) & 1u);          // round-to-nearest-even
  return (unsigned short)(u >> 16);
}
__device__ inline float bf2f(unsigned short h) {
  unsigned u = ((unsigned)h) << 16;
  return __builtin_bit_cast(float, u);
}
__device__ inline unsigned pack2bf(float lo, float hi) {
  return (unsigned)f2bf(lo) | ((unsigned)f2bf(hi) << 16);
}

// ---------------- Stage A: V[n', i] = sum_j W[k,i,j] * t_bn[n', j] ----------------
// grid 256: block = (k, half); 128 rows n' = k*256 + half*128 + m
__global__ __launch_bounds__(256, 2) void k_stageA(
    const float* __restrict__ t, const float* __restrict__ W,
    const float* __restrict__ gamma1, const float* __restrict__ beta1,
    const float* __restrict__ mean1, const float* __restrict__ var1,
    unsigned short* __restrict__ V) {
  __shared__ short LA[128 * DPAD];  // Tl[m][j] = bf16(t_bn[rowbase+m, j])
  __shared__ short LB[128 * DPAD];  // Wl[i][j] = bf16(W[k, i, j])
  const int tid = threadIdx.x;
  const int c = tid & 31;
  const int rr = tid >> 5;
  const int wv_ = tid >> 6;
  const int lane = tid & 63;
  const int l16 = lane & 15;
  const int quad = lane >> 4;

  const int k = blockIdx.x >> 1;           // [0,128)
  const int half = blockIdx.x & 1;
  const int rowbase = k * 256 + half * 128;

  f32x4 g  = *(const f32x4*)(gamma1 + c * 4);
  f32x4 be = *(const f32x4*)(beta1  + c * 4);
  f32x4 mu = *(const f32x4*)(mean1  + c * 4);
  f32x4 va = *(const f32x4*)(var1   + c * 4);
  f32x4 sc, bi;
  for (int q = 0; q < 4; ++q) {
    sc[q] = g[q] * rsqrtf(va[q] + BN_EPS);
    bi[q] = be[q] - mu[q] * sc[q];
  }
  const float* tbase = t + (size_t)rowbase * 128;
  const float* wbase = W + (size_t)k * 16384;

  // --- burst: all 32 staging loads issued back-to-back (32 KB/wave in flight)
  f32x4 tv[16], wvv[16];
#pragma unroll
  for (int it = 0; it < 16; ++it) {
    const int m = it * 8 + rr;
    tv[it]  = *(const f32x4*)(tbase + m * 128 + c * 4);
    wvv[it] = *(const f32x4*)(wbase + m * 128 + c * 4);
  }
  // --- drain: convert + LDS-write (single implicit vmcnt wall)
#pragma unroll
  for (int it = 0; it < 16; ++it) {
    const int m = it * 8 + rr;
    s16x4 tb, wb;
    for (int q = 0; q < 4; ++q) tb[q] = (short)f2bf(tv[it][q] * sc[q] + bi[q]);
    for (int q = 0; q < 4; ++q) wb[q] = (short)f2bf(wvv[it][q]);
    *(s16x4*)(&LA[m * DPAD + c * 4]) = tb;
    *(s16x4*)(&LB[m * DPAD + c * 4]) = wb;
  }
  __syncthreads();

  f32x4 acc[2][8];
  for (int mt = 0; mt < 2; ++mt)
    for (int nt = 0; nt < 8; ++nt) acc[mt][nt] = (f32x4){0.f, 0.f, 0.f, 0.f};

  // swapped operands: acc = mfma(Wfrag, Tfrag) -> D[i-part(row), n'-part(col)]
  __builtin_amdgcn_s_setprio(1);
#pragma unroll
  for (int ks = 0; ks < 4; ++ks) {
    const int K0 = ks * 32 + quad * 8;
    bf16x8 a[2], b[8];
    for (int mt = 0; mt < 2; ++mt)
      a[mt] = *(const bf16x8*)(&LA[(wv_ * 32 + mt * 16 + l16) * DPAD + K0]);
    for (int nt = 0; nt < 8; ++nt)
      b[nt] = *(const bf16x8*)(&LB[(nt * 16 + l16) * DPAD + K0]);
    for (int mt = 0; mt < 2; ++mt)
      for (int nt = 0; nt < 8; ++nt)
        acc[mt][nt] = __builtin_amdgcn_mfma_f32_16x16x32_bf16(b[nt], a[mt], acc[mt][nt], 0, 0, 0);
  }
  __builtin_amdgcn_s_setprio(0);

  // lane holds i = nt*16 + quad*4 + {0..3} of row n' = rowbase + wv*32 + mt*16 + l16
  for (int mt = 0; mt < 2; ++mt) {
    const size_t np = (size_t)(rowbase + wv_ * 32 + mt * 16 + l16) * 128;
    for (int nt = 0; nt < 8; ++nt) {
      unsigned two[2];
      two[0] = pack2bf(acc[mt][nt][0], acc[mt][nt][1]);
      two[1] = pack2bf(acc[mt][nt][2], acc[mt][nt][3]);
      *(uint2*)(V + np + nt * 16 + quad * 4) = *(uint2*)two;
    }
  }
}

// ------- Stage B + dot: out[n'] = sum_i (sum_a h_bn[n',a] r[low*128+a, i]) * V[n',i] -------
// grid 256: block = low; rows n' = kk*256 + low, kk in [0,128)
__global__ __launch_bounds__(256, 2) void k_bdot(
    const float* __restrict__ h, const float* __restrict__ r,
    const float* __restrict__ gamma0, const float* __restrict__ beta0,
    const float* __restrict__ mean0, const float* __restrict__ var0,
    const unsigned short* __restrict__ V, float* __restrict__ out) {
  __shared__ short LA[128 * DPAD];  // Hl[kk][a] = bf16(h_bn[kk*256+low, a])
  __shared__ short LB[128 * DPAD];  // Rl[i][a]  = bf16(r[low*128+a, i])   (transposed)
  const int tid = threadIdx.x;
  const int c = tid & 31;
  const int rr = tid >> 5;
  const int wv_ = tid >> 6;
  const int lane = tid & 63;
  const int l16 = lane & 15;
  const int quad = lane >> 4;

  const int low = blockIdx.x;              // [0,256)

  f32x4 g  = *(const f32x4*)(gamma0 + c * 4);
  f32x4 be = *(const f32x4*)(beta0  + c * 4);
  f32x4 mu = *(const f32x4*)(mean0  + c * 4);
  f32x4 va = *(const f32x4*)(var0   + c * 4);
  f32x4 sc, bi;
  for (int q = 0; q < 4; ++q) {
    sc[q] = g[q] * rsqrtf(va[q] + BN_EPS);
    bi[q] = be[q] - mu[q] * sc[q];
  }

  // --- burst: all 32 staging loads (16 h-rows + 16 r for the transpose)
  f32x4 hv[16], rv[4][4];
#pragma unroll
  for (int it = 0; it < 16; ++it) {
    const int kk = it * 8 + rr;
    hv[it] = *(const f32x4*)(h + ((size_t)(kk * 256 + low)) * 128 + c * 4);
  }
#pragma unroll
  for (int it = 0; it < 4; ++it) {
    const int a0 = it * 32 + rr * 4;
    for (int v = 0; v < 4; ++v)
      rv[it][v] = *(const f32x4*)(r + ((size_t)(low * 128 + a0 + v)) * 128 + c * 4);
  }
  // --- drain: convert + LDS-write
#pragma unroll
  for (int it = 0; it < 16; ++it) {
    const int kk = it * 8 + rr;
    s16x4 hb;
    for (int q = 0; q < 4; ++q) hb[q] = (short)f2bf(hv[it][q] * sc[q] + bi[q]);
    *(s16x4*)(&LA[kk * DPAD + c * 4]) = hb;
  }
#pragma unroll
  for (int it = 0; it < 4; ++it) {
    const int a0 = it * 32 + rr * 4;
    for (int u = 0; u < 4; ++u) {
      s16x4 w;
      for (int v = 0; v < 4; ++v) w[v] = (short)f2bf(rv[it][v][u]);
      *(s16x4*)(&LB[(c * 4 + u) * DPAD + a0]) = w;
    }
  }
  __syncthreads();

  f32x4 acc[2][8];
  for (int mt = 0; mt < 2; ++mt)
    for (int nt = 0; nt < 8; ++nt) acc[mt][nt] = (f32x4){0.f, 0.f, 0.f, 0.f};

  // swapped operands: acc = mfma(Rfrag, Hfrag) -> D[i-part(row), kk-part(col)]
  __builtin_amdgcn_s_setprio(1);
#pragma unroll
  for (int ks = 0; ks < 4; ++ks) {
    const int K0 = ks * 32 + quad * 8;
    bf16x8 a[2], b[8];
    for (int mt = 0; mt < 2; ++mt)
      a[mt] = *(const bf16x8*)(&LA[(wv_ * 32 + mt * 16 + l16) * DPAD + K0]);
    for (int nt = 0; nt < 8; ++nt)
      b[nt] = *(const bf16x8*)(&LB[(nt * 16 + l16) * DPAD + K0]);
    for (int mt = 0; mt < 2; ++mt)
      for (int nt = 0; nt < 8; ++nt)
        acc[mt][nt] = __builtin_amdgcn_mfma_f32_16x16x32_bf16(b[nt], a[mt], acc[mt][nt], 0, 0, 0);
  }
  __builtin_amdgcn_s_setprio(0);

  // fused dot: lane holds u[n', i=nt*16+quad*4+q] fp32 for row n' = kk*256+low,
  // kk = wv*32 + mt*16 + l16. Load matching V bf16, FMA, reduce across quads.
  for (int mt = 0; mt < 2; ++mt) {
    const int kk = wv_ * 32 + mt * 16 + l16;
    const size_t np = ((size_t)kk * 256 + low) * 128;
    float s = 0.f;
    for (int nt = 0; nt < 8; ++nt) {
      const uint2 vv = *(const uint2*)(V + np + nt * 16 + quad * 4);
      s += acc[mt][nt][0] * bf2f((unsigned short)(vv.x & 0xFFFFu));
      s += acc[mt][nt][1] * bf2f((unsigned short)(vv.x >> 16));
      s += acc[mt][nt][2] * bf2f((unsigned short)(vv.y & 0xFFFFu));
      s += acc[mt][nt][3] * bf2f((unsigned short)(vv.y >> 16));
    }
    s += __shfl_xor(s, 16, 64);
    s += __shfl_xor(s, 32, 64);
    if (quad == 0) out[(size_t)kk * 256 + low] = s;
  }
}

extern "C" void kernel_launch(void* const* d_in, const int* in_sizes, int n_in,
                              void* d_out, int out_size, void* d_ws, size_t ws_size,
                              hipStream_t stream) {
  const float* h      = (const float*)d_in[0];
  const float* r      = (const float*)d_in[1];
  const float* t      = (const float*)d_in[2];
  const float* W      = (const float*)d_in[3];
  const float* gamma0 = (const float*)d_in[4];
  const float* beta0  = (const float*)d_in[5];
  const float* mean0  = (const float*)d_in[6];
  const float* var0   = (const float*)d_in[7];
  const float* gamma1 = (const float*)d_in[8];
  const float* beta1  = (const float*)d_in[9];
  const float* mean1  = (const float*)d_in[10];
  const float* var1   = (const float*)d_in[11];
  float* out = (float*)d_out;

  unsigned short* V = (unsigned short*)d_ws;   // 32768*128 bf16 = 8 MB

  k_stageA<<<256, 256, 0, stream>>>(t, W, gamma1, beta1, mean1, var1, V);
  k_bdot<<<256, 256, 0, stream>>>(h, r, gamma0, beta0, mean0, var0, V, out);
}